// Round 12
// baseline (492.335 us; speedup 1.0000x reference)
//
#include <hip/hip_runtime.h>

#define BB 16
#define NN 2048
#define MM 2048
#define EPSF 1e-9f
#define SKIPT (-135.0f)   // exp2(arg) == 0 below this

typedef float v2f __attribute__((ext_vector_type(2)));
typedef float v4f __attribute__((ext_vector_type(4)));

constexpr int CH = 128;    // stream chunk length
// R12: R11 body with CH=128. grid = BB x 2 halves x 16 chunks = 512 blocks
// (2/CU, 16 waves/CU). Halves block count, per-output atomic contention
// (32->16 way) and prelude total vs R11. VGPR cap stays 256 (512 threads,
// no min-waves) -- the empirically safe zone for the pk-asm body.

// ---- packed fp32 helpers (VOP3P; verified R4/R6/R9/R11) ----
__device__ __forceinline__ v2f pk_add(v2f a, v2f b){ v2f d; asm("v_pk_add_f32 %0, %1, %2" : "=v"(d) : "v"(a), "v"(b)); return d; }
__device__ __forceinline__ v2f pk_mul(v2f a, v2f b){ v2f d; asm("v_pk_mul_f32 %0, %1, %2" : "=v"(d) : "v"(a), "v"(b)); return d; }
__device__ __forceinline__ v2f pk_fma(v2f a, v2f b, v2f c){ v2f d; asm("v_pk_fma_f32 %0, %1, %2, %3" : "=v"(d) : "v"(a), "v"(b), "v"(c)); return d; }
__device__ __forceinline__ v2f lo2(v4f a){ return __builtin_shufflevector(a, a, 0, 1); }
__device__ __forceinline__ v2f hi2(v4f a){ return __builtin_shufflevector(a, a, 2, 3); }

// ---------------- init ----------------
__global__ __launch_bounds__(256) void init_kernel(
    const float* __restrict__ xyz1, const float* __restrict__ xyz2,
    float4* __restrict__ P1, float4* __restrict__ P2,
    float* __restrict__ remR0,
    float* __restrict__ stRS, float* __restrict__ stU,
    float* __restrict__ stS, float* __restrict__ stT,
    float* __restrict__ out)
{
    const int t = blockIdx.x * 256 + threadIdx.x;   // 0 .. BB*NN-1
    if (t < BB * NN) {
        P1[t] = make_float4(xyz1[3*t+0], xyz1[3*t+1], xyz1[3*t+2], 0.0f);
        stRS[t] = 0.0f; stRS[BB*NN + t] = 0.0f;
        stU[t]  = 0.0f; stU[BB*NN + t]  = 0.0f;
    }
    if (t < BB * MM) {
        P2[t] = make_float4(xyz2[3*t+0], xyz2[3*t+1], xyz2[3*t+2], 0.0f);
        remR0[t] = 1.0f;
        stS[t] = 0.0f; stS[BB*MM + t] = 0.0f;
        stT[t] = 0.0f; stT[BB*MM + t] = 0.0f;
    }
    if (t < BB) out[t] = 0.0f;
}

// ---------------- rowInit: stRS[1] += sum_l exp(coef0*d2) (remR=1) ----------------
__global__ __launch_bounds__(512) void rowInit(
    const float4* __restrict__ P1, const float4* __restrict__ P2,
    float* __restrict__ stRSacc, float coef)
{
    __shared__ v4f tA[CH / 2];                    // {-x0,-x1,-y0,-y1}
    __shared__ v2f tZ[CH / 2];                    // {-z0,-z1}
    const int chunks = MM / CH;                   // 16
    const int bpb = (NN / 1024) * chunks;         // 32
    const int batch = blockIdx.x / bpb;
    const int rem   = blockIdx.x % bpb;
    const int rg    = rem / chunks;               // 0..1
    const int ic    = rem % chunks;
    const int t     = threadIdx.x;                // 0..511

    const int row0 = batch * NN + rg * 1024 + t;
    const int row1 = row0 + 512;
    const float4 p0 = P1[row0];                   // hoisted: in flight during staging
    const float4 p1 = P1[row1];

    if (t < CH / 2) {
        const int gi = batch * MM + ic * CH + 2 * t;
        const float4 a = P2[gi];
        const float4 b = P2[gi + 1];
        tA[t] = (v4f){-a.x, -b.x, -a.y, -b.y};
        tZ[t] = (v2f){-a.z, -b.z};
    }
    __syncthreads();

    const v2f ax0 = {p0.x, p0.x}, ay0 = {p0.y, p0.y}, az0 = {p0.z, p0.z};
    const v2f ax1 = {p1.x, p1.x}, ay1 = {p1.y, p1.y}, az1 = {p1.z, p1.z};
    const v2f cf = {coef, coef};
    v2f rs0 = {0.0f, 0.0f}, rs1 = {0.0f, 0.0f};
#pragma unroll 4
    for (int k = 0; k < CH / 2; ++k) {
        const v4f A = tA[k];
        const v2f Zn = tZ[k];
        const v2f Xn = lo2(A), Yn = hi2(A);
        const v2f dx0 = pk_add(Xn, ax0), dy0 = pk_add(Yn, ay0), dz0 = pk_add(Zn, az0);
        const v2f d20 = pk_fma(dx0, dx0, pk_fma(dy0, dy0, pk_mul(dz0, dz0)));
        const v2f dx1 = pk_add(Xn, ax1), dy1 = pk_add(Yn, ay1), dz1 = pk_add(Zn, az1);
        const v2f d21 = pk_fma(dx1, dx1, pk_fma(dy1, dy1, pk_mul(dz1, dz1)));
        const v2f g0 = pk_mul(d20, cf), g1 = pk_mul(d21, cf);
        const float gm = fmaxf(fmaxf(g0.x, g0.y), fmaxf(g1.x, g1.y));
        if (__ballot(gm > SKIPT)) {
            v2f e0, e1;
            e0.x = __builtin_amdgcn_exp2f(g0.x); e0.y = __builtin_amdgcn_exp2f(g0.y);
            e1.x = __builtin_amdgcn_exp2f(g1.x); e1.y = __builtin_amdgcn_exp2f(g1.y);
            rs0 = pk_add(rs0, e0);
            rs1 = pk_add(rs1, e1);
        }
    }
    atomicAdd(&stRSacc[row0], rs0.x + rs0.y);
    atomicAdd(&stRSacc[row1], rs1.x + rs1.y);
}

// ---------------- colK: row-finalize prelude + column-partial stream ----------------
// MODE 0: j==0 (remL=1). MODE 1: general. MODE 2: j==9 (coef==0 -> e=scale).
template<int MODE, bool SPARSE>
__global__ __launch_bounds__(512) void colK(
    const float4* __restrict__ P1, const float4* __restrict__ P2,
    const float* __restrict__ stRSr, const float* __restrict__ stUr,
    float* __restrict__ stRSz, float* __restrict__ stUz,
    const float* __restrict__ remLr, float* __restrict__ remLw,
    const float* __restrict__ scaler, float* __restrict__ scalew,
    float* __restrict__ stS, float* __restrict__ stT,
    float coef)
{
    __shared__ v4f tA[CH / 2];                    // {-x0,-x1,-y0,-y1}  (P1 rows)
    __shared__ v4f tB[CH / 2];                    // {-z0,-z1, sc0, sc1}
    __shared__ float sSc[CH];
    const int chunks = NN / CH;                   // 16
    const int bpb = (MM / 1024) * chunks;         // 32
    const int batch = blockIdx.x / bpb;
    const int rem   = blockIdx.x % bpb;
    const int cg    = rem / chunks;               // 0..1
    const int ic    = rem % chunks;
    const int t     = threadIdx.x;                // 0..511

    const int col0 = batch * MM + cg * 1024 + t;
    const int col1 = col0 + 512;
    const float4 q0 = P2[col0];                   // hoisted above prelude
    const float4 q1 = P2[col1];
    float4 a, b;
    if (t < CH / 2) {                             // hoisted staging loads
        const int gi2 = batch * NN + ic * CH + 2 * t;
        a = P1[gi2];
        b = P1[gi2 + 1];
    }

    // prelude: finalize rows of this chunk (duplicated by 2 cg-blocks; identical values)
    if (t < CH) {
        const int gi = batch * NN + ic * CH + t;
        float L;
        if (MODE == 0) L = 1.0f;
        else           L = fmaxf(remLr[gi] - scaler[gi] * stUr[gi], 0.0f);
        remLw[gi] = L;
        const float sc = L / (stRSr[gi] + EPSF);
        scalew[gi] = sc;
        sSc[t] = sc;
        stRSz[gi] = 0.0f; stUz[gi] = 0.0f;        // zero next accumulation parity
    }
    __syncthreads();
    if (t < CH / 2) {
        tA[t] = (v4f){-a.x, -b.x, -a.y, -b.y};
        tB[t] = (v4f){-a.z, -b.z, sSc[2*t], sSc[2*t + 1]};
    }
    __syncthreads();

    const v2f ax0 = {q0.x, q0.x}, ay0 = {q0.y, q0.y}, az0 = {q0.z, q0.z};
    const v2f ax1 = {q1.x, q1.x}, ay1 = {q1.y, q1.y}, az1 = {q1.z, q1.z};
    const v2f cf = {coef, coef};
    v2f s0 = {0.0f, 0.0f}, s1 = {0.0f, 0.0f};
    v2f tt0 = {0.0f, 0.0f}, tt1 = {0.0f, 0.0f};
#pragma unroll 4
    for (int k = 0; k < CH / 2; ++k) {
        const v4f A = tA[k], B = tB[k];
        const v2f Xn = lo2(A), Yn = hi2(A), Zn = lo2(B), Wsc = hi2(B);
        const v2f dx0 = pk_add(Xn, ax0), dy0 = pk_add(Yn, ay0), dz0 = pk_add(Zn, az0);
        const v2f d20 = pk_fma(dx0, dx0, pk_fma(dy0, dy0, pk_mul(dz0, dz0)));
        const v2f dx1 = pk_add(Xn, ax1), dy1 = pk_add(Yn, ay1), dz1 = pk_add(Zn, az1);
        const v2f d21 = pk_fma(dx1, dx1, pk_fma(dy1, dy1, pk_mul(dz1, dz1)));
        if (SPARSE) {
            const v2f g0 = pk_mul(d20, cf), g1 = pk_mul(d21, cf);
            const float gm = fmaxf(fmaxf(g0.x, g0.y), fmaxf(g1.x, g1.y));
            if (__ballot(gm > SKIPT)) {
                v2f e0, e1, sq0, sq1;
                e0.x = __builtin_amdgcn_exp2f(g0.x); e0.y = __builtin_amdgcn_exp2f(g0.y);
                e1.x = __builtin_amdgcn_exp2f(g1.x); e1.y = __builtin_amdgcn_exp2f(g1.y);
                e0 = pk_mul(e0, Wsc);
                e1 = pk_mul(e1, Wsc);
                sq0.x = __builtin_amdgcn_sqrtf(d20.x); sq0.y = __builtin_amdgcn_sqrtf(d20.y);
                sq1.x = __builtin_amdgcn_sqrtf(d21.x); sq1.y = __builtin_amdgcn_sqrtf(d21.y);
                s0 = pk_add(s0, e0);  tt0 = pk_fma(e0, sq0, tt0);
                s1 = pk_add(s1, e1);  tt1 = pk_fma(e1, sq1, tt1);
            }
        } else {
            v2f e0, e1, sq0, sq1;
            if (MODE == 2) { e0 = Wsc; e1 = Wsc; }
            else {
                const v2f g0 = pk_mul(d20, cf), g1 = pk_mul(d21, cf);
                e0.x = __builtin_amdgcn_exp2f(g0.x); e0.y = __builtin_amdgcn_exp2f(g0.y);
                e1.x = __builtin_amdgcn_exp2f(g1.x); e1.y = __builtin_amdgcn_exp2f(g1.y);
                e0 = pk_mul(e0, Wsc);
                e1 = pk_mul(e1, Wsc);
            }
            sq0.x = __builtin_amdgcn_sqrtf(d20.x); sq0.y = __builtin_amdgcn_sqrtf(d20.y);
            sq1.x = __builtin_amdgcn_sqrtf(d21.x); sq1.y = __builtin_amdgcn_sqrtf(d21.y);
            s0 = pk_add(s0, e0);  tt0 = pk_fma(e0, sq0, tt0);
            s1 = pk_add(s1, e1);  tt1 = pk_fma(e1, sq1, tt1);
        }
    }
    atomicAdd(&stS[col0], s0.x + s0.y);
    atomicAdd(&stT[col0], tt0.x + tt0.y);
    atomicAdd(&stS[col1], s1.x + s1.y);
    atomicAdd(&stT[col1], tt1.x + tt1.y);
}

// ---------------- rowK: col-finalize prelude + row-partial stream ----------------
// MODE 1: general. MODE 2: j==8 (rs = sum remR_9, u at coefP direct).
template<int MODE, bool SPARSE>
__global__ __launch_bounds__(512) void rowK(
    const float4* __restrict__ P1, const float4* __restrict__ P2,
    const float* __restrict__ stSr, const float* __restrict__ stTr,
    float* __restrict__ stSz, float* __restrict__ stTz,
    const float* __restrict__ remRr, float* __restrict__ remRw,
    float* __restrict__ stRS, float* __restrict__ stU,
    float* __restrict__ out,
    float coefP, float coefN)
{
    __shared__ v4f tA[CH / 2];                    // {-x0,-x1,-y0,-y1}  (P2 cols)
    __shared__ v4f tB[CH / 2];                    // {-z0,-z1, Rn0, Rn1}
    __shared__ v2f tC[CH / 2];                    // {pc0, pc1}
    __shared__ float sRn[CH], sPcs[CH];
    const int chunks = MM / CH;                   // 16
    const int bpb = (NN / 1024) * chunks;         // 32
    const int batch = blockIdx.x / bpb;
    const int rem   = blockIdx.x % bpb;
    const int rg    = rem / chunks;               // 0..1
    const int ic    = rem % chunks;
    const int t     = threadIdx.x;                // 0..511

    const int row0 = batch * NN + rg * 1024 + t;
    const int row1 = row0 + 512;
    const float4 p0 = P1[row0];                   // hoisted above prelude
    const float4 p1 = P1[row1];
    float4 a, b;
    if (t < CH / 2) {                             // hoisted staging loads
        const int gl2 = batch * MM + ic * CH + 2 * t;
        a = P2[gl2];
        b = P2[gl2 + 1];
    }

    // prelude: finalize cols of this chunk (duplicated by 2 rg-blocks; identical values)
    float c = 0.0f;
    if (t < CH) {
        const int gl = batch * MM + ic * CH + t;
        const float R  = remRr[gl];
        const float s  = stSr[gl];
        const float t2 = stTr[gl];
        const float sumr = s * R;
        const float cons = fminf(R / (sumr + EPSF), 1.0f);
        const float pcol = R * cons;
        const float Rn   = fmaxf(R - sumr * cons, 0.0f);
        remRw[gl] = Rn;
        sRn[t]  = Rn;
        sPcs[t] = pcol;
        stSz[gl] = 0.0f; stTz[gl] = 0.0f;         // zero next accumulation parity
        if (rg == 0) c = pcol * t2;               // cost contribution (once per chunk)
    }
    if (rg == 0) {
#pragma unroll
        for (int off = 32; off > 0; off >>= 1) c += __shfl_xor(c, off, 64);
        if ((t & 63) == 0 && t < CH) atomicAdd(out + batch, c);   // lane 0 of waves 0,1
    }
    __syncthreads();
    if (t < CH / 2) {
        tA[t] = (v4f){-a.x, -b.x, -a.y, -b.y};
        tB[t] = (v4f){-a.z, -b.z, sRn[2*t], sRn[2*t + 1]};
        tC[t] = (v2f){sPcs[2*t], sPcs[2*t + 1]};
    }
    __syncthreads();

    const v2f ax0 = {p0.x, p0.x}, ay0 = {p0.y, p0.y}, az0 = {p0.z, p0.z};
    const v2f ax1 = {p1.x, p1.x}, ay1 = {p1.y, p1.y}, az1 = {p1.z, p1.z};
    const v2f cfN = {coefN, coefN};
    const v2f cfP = {coefP, coefP};
    v2f rs0 = {0.0f, 0.0f}, rs1 = {0.0f, 0.0f};
    v2f u0  = {0.0f, 0.0f}, u1  = {0.0f, 0.0f};
#pragma unroll 4
    for (int k = 0; k < CH / 2; ++k) {
        const v4f A = tA[k], B = tB[k];
        const v2f Pc = tC[k];
        const v2f Xn = lo2(A), Yn = hi2(A), Zn = lo2(B), Rnp = hi2(B);
        const v2f dx0 = pk_add(Xn, ax0), dy0 = pk_add(Yn, ay0), dz0 = pk_add(Zn, az0);
        const v2f d20 = pk_fma(dx0, dx0, pk_fma(dy0, dy0, pk_mul(dz0, dz0)));
        const v2f dx1 = pk_add(Xn, ax1), dy1 = pk_add(Yn, ay1), dz1 = pk_add(Zn, az1);
        const v2f d21 = pk_fma(dx1, dx1, pk_fma(dy1, dy1, pk_mul(dz1, dz1)));
        if (MODE == 1) {
            const v2f g0 = pk_mul(d20, cfN), g1 = pk_mul(d21, cfN);
            bool go = true;
            if (SPARSE) {
                const float gm = fmaxf(fmaxf(g0.x, g0.y), fmaxf(g1.x, g1.y));
                go = __ballot(gm > SKIPT) != 0ull;
            }
            if (go) {
                v2f en0, en1;
                en0.x = __builtin_amdgcn_exp2f(g0.x); en0.y = __builtin_amdgcn_exp2f(g0.y);
                en1.x = __builtin_amdgcn_exp2f(g1.x); en1.y = __builtin_amdgcn_exp2f(g1.y);
                const v2f e20 = pk_mul(en0, en0), e21 = pk_mul(en1, en1);
                const v2f e40 = pk_mul(e20, e20), e41 = pk_mul(e21, e21);
                u0  = pk_fma(e40, Pc, u0);
                u1  = pk_fma(e41, Pc, u1);
                rs0 = pk_fma(en0, Rnp, rs0);
                rs1 = pk_fma(en1, Rnp, rs1);
            }
        } else {
            const v2f g0 = pk_mul(d20, cfP), g1 = pk_mul(d21, cfP);
            v2f ep0, ep1;
            ep0.x = __builtin_amdgcn_exp2f(g0.x); ep0.y = __builtin_amdgcn_exp2f(g0.y);
            ep1.x = __builtin_amdgcn_exp2f(g1.x); ep1.y = __builtin_amdgcn_exp2f(g1.y);
            u0  = pk_fma(ep0, Pc, u0);
            u1  = pk_fma(ep1, Pc, u1);
            rs0 = pk_add(rs0, Rnp);               // e_next = exp(0) = 1
            rs1 = pk_add(rs1, Rnp);
        }
    }
    atomicAdd(&stRS[row0], rs0.x + rs0.y);
    atomicAdd(&stU[row0],  u0.x + u0.y);
    atomicAdd(&stRS[row1], rs1.x + rs1.y);
    atomicAdd(&stU[row1],  u1.x + u1.y);
}

// ---------------- finCost: cost for level 9 (no state updates) ----------------
__global__ __launch_bounds__(256) void finCost(
    const float* __restrict__ stSr, const float* __restrict__ stTr,
    const float* __restrict__ remRr, float* __restrict__ out)
{
    const int idx = blockIdx.x * 256 + threadIdx.x;
    const int batch = idx / MM;
    const float R = remRr[idx];
    const float sumr = stSr[idx] * R;
    const float cons = fminf(R / (sumr + EPSF), 1.0f);
    float c = R * cons * stTr[idx];
#pragma unroll
    for (int off = 32; off > 0; off >>= 1) c += __shfl_xor(c, off, 64);
    if ((threadIdx.x & 63) == 0) atomicAdd(out + batch, c);
}

extern "C" void kernel_launch(void* const* d_in, const int* in_sizes, int n_in,
                              void* d_out, int out_size, void* d_ws, size_t ws_size,
                              hipStream_t stream)
{
    const float* xyz1 = (const float*)d_in[0];
    const float* xyz2 = (const float*)d_in[1];
    float* out = (float*)d_out;

    const int BN = BB * NN, BM = BB * MM;
    float4* P1 = (float4*)d_ws;
    float4* P2 = P1 + BN;
    float* remL  = (float*)(P2 + BM);       // [2][BN]
    float* scale = remL + 2 * BN;           // [2][BN]
    float* remR  = scale + 2 * BN;          // [2][BM]
    float* stRS  = remR + 2 * BM;           // [2][BN]
    float* stU   = stRS + 2 * BN;           // [2][BN]
    float* stS   = stU + 2 * BN;            // [2][BM]
    float* stT   = stS + 2 * BM;            // [2][BM]

    init_kernel<<<dim3(BN / 256), dim3(256), 0, stream>>>(
        xyz1, xyz2, P1, P2, remR, stRS, stU, stS, stT, out);

    // levels: j = 7..-1 -> -(4^j), then 0.  coef = level * log2(e)
    float coef[10];
    const double lv[10] = {-16384.0, -4096.0, -1024.0, -256.0, -64.0,
                           -16.0, -4.0, -1.0, -0.25, 0.0};
    for (int i = 0; i < 10; ++i) coef[i] = (float)(lv[i] * 1.4426950408889634);

    dim3 grid(BB * 2 * (NN / CH));          // 16*2*16 = 512 blocks
    dim3 fgrid(BM / 256);                   // 128
    dim3 blk(512);
    dim3 blk256(256);

    rowInit<<<grid, blk, 0, stream>>>(P1, P2, stRS + 1 * BN, coef[0]);

    for (int j = 0; j < 10; ++j) {
        const int p = j & 1, q = 1 - p;
        if (j == 0)
            colK<0, true><<<grid, blk, 0, stream>>>(P1, P2,
                stRS + q*BN, stU + q*BN, stRS + p*BN, stU + p*BN,
                remL + p*BN, remL + q*BN, scale + p*BN, scale + q*BN,
                stS + p*BM, stT + p*BM, coef[0]);
        else if (j <= 3)
            colK<1, true><<<grid, blk, 0, stream>>>(P1, P2,
                stRS + q*BN, stU + q*BN, stRS + p*BN, stU + p*BN,
                remL + p*BN, remL + q*BN, scale + p*BN, scale + q*BN,
                stS + p*BM, stT + p*BM, coef[j]);
        else if (j == 9)
            colK<2, false><<<grid, blk, 0, stream>>>(P1, P2,
                stRS + q*BN, stU + q*BN, stRS + p*BN, stU + p*BN,
                remL + p*BN, remL + q*BN, scale + p*BN, scale + q*BN,
                stS + p*BM, stT + p*BM, coef[9]);
        else
            colK<1, false><<<grid, blk, 0, stream>>>(P1, P2,
                stRS + q*BN, stU + q*BN, stRS + p*BN, stU + p*BN,
                remL + p*BN, remL + q*BN, scale + p*BN, scale + q*BN,
                stS + p*BM, stT + p*BM, coef[j]);

        if (j < 9) {
            if (j <= 2)
                rowK<1, true><<<grid, blk, 0, stream>>>(P1, P2,
                    stS + p*BM, stT + p*BM, stS + q*BM, stT + q*BM,
                    remR + p*BM, remR + q*BM,
                    stRS + p*BN, stU + p*BN, out, coef[j], coef[j+1]);
            else if (j < 8)
                rowK<1, false><<<grid, blk, 0, stream>>>(P1, P2,
                    stS + p*BM, stT + p*BM, stS + q*BM, stT + q*BM,
                    remR + p*BM, remR + q*BM,
                    stRS + p*BN, stU + p*BN, out, coef[j], coef[j+1]);
            else
                rowK<2, false><<<grid, blk, 0, stream>>>(P1, P2,
                    stS + p*BM, stT + p*BM, stS + q*BM, stT + q*BM,
                    remR + p*BM, remR + q*BM,
                    stRS + p*BN, stU + p*BN, out, coef[8], 0.0f);
        }
    }
    // level 9 cost: stS/stT parity 1, remR parity 1
    finCost<<<fgrid, blk256, 0, stream>>>(stS + 1*BM, stT + 1*BM, remR + 1*BM, out);
}

// Round 13
// 452.216 us; speedup vs baseline: 1.0887x; 1.0887x over previous
//
#include <hip/hip_runtime.h>

#define BB 16
#define NN 2048
#define MM 2048
#define EPSF 1e-9f
#define SKIPT (-135.0f)   // exp2(arg) == 0 below this

typedef float v2f __attribute__((ext_vector_type(2)));
typedef float v4f __attribute__((ext_vector_type(4)));

constexpr int CH = 64;     // stream chunk length (2 outputs/thread)
// R13 = R11 verbatim (best verified: 450.7 us, absmax 0.0).
// grid = BB x 2 halves x 32 chunks = 1024 blocks x 512 threads
// (4 blocks/CU x 8 waves = 32 waves/CU -- full occupancy, proven essential:
//  R12's 16 waves/CU cost +42 us). Pair-packed pk-fp32 tiles; VGPR cap 256
// (512 threads, no min-waves) -- the empirically safe zone for pk-asm.
// Structural floor analysis: 21 serial dispatches x ~15us fixed
// (launch+ramp+atomic-drain; grid.sync=100us on 8-XCD, streams barred by
// graph capture) + ~160us body issue = ~450us.

// ---- packed fp32 helpers (VOP3P; verified R4/R6/R9/R11) ----
__device__ __forceinline__ v2f pk_add(v2f a, v2f b){ v2f d; asm("v_pk_add_f32 %0, %1, %2" : "=v"(d) : "v"(a), "v"(b)); return d; }
__device__ __forceinline__ v2f pk_mul(v2f a, v2f b){ v2f d; asm("v_pk_mul_f32 %0, %1, %2" : "=v"(d) : "v"(a), "v"(b)); return d; }
__device__ __forceinline__ v2f pk_fma(v2f a, v2f b, v2f c){ v2f d; asm("v_pk_fma_f32 %0, %1, %2, %3" : "=v"(d) : "v"(a), "v"(b), "v"(c)); return d; }
__device__ __forceinline__ v2f lo2(v4f a){ return __builtin_shufflevector(a, a, 0, 1); }
__device__ __forceinline__ v2f hi2(v4f a){ return __builtin_shufflevector(a, a, 2, 3); }

// ---------------- init ----------------
__global__ __launch_bounds__(256) void init_kernel(
    const float* __restrict__ xyz1, const float* __restrict__ xyz2,
    float4* __restrict__ P1, float4* __restrict__ P2,
    float* __restrict__ remR0,
    float* __restrict__ stRS, float* __restrict__ stU,
    float* __restrict__ stS, float* __restrict__ stT,
    float* __restrict__ out)
{
    const int t = blockIdx.x * 256 + threadIdx.x;   // 0 .. BB*NN-1
    if (t < BB * NN) {
        P1[t] = make_float4(xyz1[3*t+0], xyz1[3*t+1], xyz1[3*t+2], 0.0f);
        stRS[t] = 0.0f; stRS[BB*NN + t] = 0.0f;
        stU[t]  = 0.0f; stU[BB*NN + t]  = 0.0f;
    }
    if (t < BB * MM) {
        P2[t] = make_float4(xyz2[3*t+0], xyz2[3*t+1], xyz2[3*t+2], 0.0f);
        remR0[t] = 1.0f;
        stS[t] = 0.0f; stS[BB*MM + t] = 0.0f;
        stT[t] = 0.0f; stT[BB*MM + t] = 0.0f;
    }
    if (t < BB) out[t] = 0.0f;
}

// ---------------- rowInit: stRS[1] += sum_l exp(coef0*d2) (remR=1) ----------------
__global__ __launch_bounds__(512) void rowInit(
    const float4* __restrict__ P1, const float4* __restrict__ P2,
    float* __restrict__ stRSacc, float coef)
{
    __shared__ v4f tA[CH / 2];                    // {-x0,-x1,-y0,-y1}
    __shared__ v2f tZ[CH / 2];                    // {-z0,-z1}
    const int chunks = MM / CH;                   // 32
    const int bpb = (NN / 1024) * chunks;         // 64
    const int batch = blockIdx.x / bpb;
    const int rem   = blockIdx.x % bpb;
    const int rg    = rem / chunks;               // 0..1
    const int ic    = rem % chunks;
    const int t     = threadIdx.x;                // 0..511

    const int row0 = batch * NN + rg * 1024 + t;
    const int row1 = row0 + 512;
    const float4 p0 = P1[row0];                   // hoisted: in flight during staging
    const float4 p1 = P1[row1];

    if (t < CH / 2) {
        const int gi = batch * MM + ic * CH + 2 * t;
        const float4 a = P2[gi];
        const float4 b = P2[gi + 1];
        tA[t] = (v4f){-a.x, -b.x, -a.y, -b.y};
        tZ[t] = (v2f){-a.z, -b.z};
    }
    __syncthreads();

    const v2f ax0 = {p0.x, p0.x}, ay0 = {p0.y, p0.y}, az0 = {p0.z, p0.z};
    const v2f ax1 = {p1.x, p1.x}, ay1 = {p1.y, p1.y}, az1 = {p1.z, p1.z};
    const v2f cf = {coef, coef};
    v2f rs0 = {0.0f, 0.0f}, rs1 = {0.0f, 0.0f};
#pragma unroll 4
    for (int k = 0; k < CH / 2; ++k) {
        const v4f A = tA[k];
        const v2f Zn = tZ[k];
        const v2f Xn = lo2(A), Yn = hi2(A);
        const v2f dx0 = pk_add(Xn, ax0), dy0 = pk_add(Yn, ay0), dz0 = pk_add(Zn, az0);
        const v2f d20 = pk_fma(dx0, dx0, pk_fma(dy0, dy0, pk_mul(dz0, dz0)));
        const v2f dx1 = pk_add(Xn, ax1), dy1 = pk_add(Yn, ay1), dz1 = pk_add(Zn, az1);
        const v2f d21 = pk_fma(dx1, dx1, pk_fma(dy1, dy1, pk_mul(dz1, dz1)));
        const v2f g0 = pk_mul(d20, cf), g1 = pk_mul(d21, cf);
        const float gm = fmaxf(fmaxf(g0.x, g0.y), fmaxf(g1.x, g1.y));
        if (__ballot(gm > SKIPT)) {
            v2f e0, e1;
            e0.x = __builtin_amdgcn_exp2f(g0.x); e0.y = __builtin_amdgcn_exp2f(g0.y);
            e1.x = __builtin_amdgcn_exp2f(g1.x); e1.y = __builtin_amdgcn_exp2f(g1.y);
            rs0 = pk_add(rs0, e0);
            rs1 = pk_add(rs1, e1);
        }
    }
    atomicAdd(&stRSacc[row0], rs0.x + rs0.y);
    atomicAdd(&stRSacc[row1], rs1.x + rs1.y);
}

// ---------------- colK: row-finalize prelude + column-partial stream ----------------
// MODE 0: j==0 (remL=1). MODE 1: general. MODE 2: j==9 (coef==0 -> e=scale).
template<int MODE, bool SPARSE>
__global__ __launch_bounds__(512) void colK(
    const float4* __restrict__ P1, const float4* __restrict__ P2,
    const float* __restrict__ stRSr, const float* __restrict__ stUr,
    float* __restrict__ stRSz, float* __restrict__ stUz,
    const float* __restrict__ remLr, float* __restrict__ remLw,
    const float* __restrict__ scaler, float* __restrict__ scalew,
    float* __restrict__ stS, float* __restrict__ stT,
    float coef)
{
    __shared__ v4f tA[CH / 2];                    // {-x0,-x1,-y0,-y1}  (P1 rows)
    __shared__ v4f tB[CH / 2];                    // {-z0,-z1, sc0, sc1}
    __shared__ float sSc[CH];
    const int chunks = NN / CH;                   // 32
    const int bpb = (MM / 1024) * chunks;         // 64
    const int batch = blockIdx.x / bpb;
    const int rem   = blockIdx.x % bpb;
    const int cg    = rem / chunks;               // 0..1
    const int ic    = rem % chunks;
    const int t     = threadIdx.x;                // 0..511

    const int col0 = batch * MM + cg * 1024 + t;
    const int col1 = col0 + 512;
    const float4 q0 = P2[col0];                   // hoisted above prelude
    const float4 q1 = P2[col1];
    float4 a, b;
    if (t < CH / 2) {                             // hoisted staging loads
        const int gi2 = batch * NN + ic * CH + 2 * t;
        a = P1[gi2];
        b = P1[gi2 + 1];
    }

    // prelude: finalize rows of this chunk (duplicated by 2 cg-blocks; identical values)
    if (t < CH) {
        const int gi = batch * NN + ic * CH + t;
        float L;
        if (MODE == 0) L = 1.0f;
        else           L = fmaxf(remLr[gi] - scaler[gi] * stUr[gi], 0.0f);
        remLw[gi] = L;
        const float sc = L / (stRSr[gi] + EPSF);
        scalew[gi] = sc;
        sSc[t] = sc;
        stRSz[gi] = 0.0f; stUz[gi] = 0.0f;        // zero next accumulation parity
    }
    __syncthreads();
    if (t < CH / 2) {
        tA[t] = (v4f){-a.x, -b.x, -a.y, -b.y};
        tB[t] = (v4f){-a.z, -b.z, sSc[2*t], sSc[2*t + 1]};
    }
    __syncthreads();

    const v2f ax0 = {q0.x, q0.x}, ay0 = {q0.y, q0.y}, az0 = {q0.z, q0.z};
    const v2f ax1 = {q1.x, q1.x}, ay1 = {q1.y, q1.y}, az1 = {q1.z, q1.z};
    const v2f cf = {coef, coef};
    v2f s0 = {0.0f, 0.0f}, s1 = {0.0f, 0.0f};
    v2f tt0 = {0.0f, 0.0f}, tt1 = {0.0f, 0.0f};
#pragma unroll 4
    for (int k = 0; k < CH / 2; ++k) {
        const v4f A = tA[k], B = tB[k];
        const v2f Xn = lo2(A), Yn = hi2(A), Zn = lo2(B), Wsc = hi2(B);
        const v2f dx0 = pk_add(Xn, ax0), dy0 = pk_add(Yn, ay0), dz0 = pk_add(Zn, az0);
        const v2f d20 = pk_fma(dx0, dx0, pk_fma(dy0, dy0, pk_mul(dz0, dz0)));
        const v2f dx1 = pk_add(Xn, ax1), dy1 = pk_add(Yn, ay1), dz1 = pk_add(Zn, az1);
        const v2f d21 = pk_fma(dx1, dx1, pk_fma(dy1, dy1, pk_mul(dz1, dz1)));
        if (SPARSE) {
            const v2f g0 = pk_mul(d20, cf), g1 = pk_mul(d21, cf);
            const float gm = fmaxf(fmaxf(g0.x, g0.y), fmaxf(g1.x, g1.y));
            if (__ballot(gm > SKIPT)) {
                v2f e0, e1, sq0, sq1;
                e0.x = __builtin_amdgcn_exp2f(g0.x); e0.y = __builtin_amdgcn_exp2f(g0.y);
                e1.x = __builtin_amdgcn_exp2f(g1.x); e1.y = __builtin_amdgcn_exp2f(g1.y);
                e0 = pk_mul(e0, Wsc);
                e1 = pk_mul(e1, Wsc);
                sq0.x = __builtin_amdgcn_sqrtf(d20.x); sq0.y = __builtin_amdgcn_sqrtf(d20.y);
                sq1.x = __builtin_amdgcn_sqrtf(d21.x); sq1.y = __builtin_amdgcn_sqrtf(d21.y);
                s0 = pk_add(s0, e0);  tt0 = pk_fma(e0, sq0, tt0);
                s1 = pk_add(s1, e1);  tt1 = pk_fma(e1, sq1, tt1);
            }
        } else {
            v2f e0, e1, sq0, sq1;
            if (MODE == 2) { e0 = Wsc; e1 = Wsc; }
            else {
                const v2f g0 = pk_mul(d20, cf), g1 = pk_mul(d21, cf);
                e0.x = __builtin_amdgcn_exp2f(g0.x); e0.y = __builtin_amdgcn_exp2f(g0.y);
                e1.x = __builtin_amdgcn_exp2f(g1.x); e1.y = __builtin_amdgcn_exp2f(g1.y);
                e0 = pk_mul(e0, Wsc);
                e1 = pk_mul(e1, Wsc);
            }
            sq0.x = __builtin_amdgcn_sqrtf(d20.x); sq0.y = __builtin_amdgcn_sqrtf(d20.y);
            sq1.x = __builtin_amdgcn_sqrtf(d21.x); sq1.y = __builtin_amdgcn_sqrtf(d21.y);
            s0 = pk_add(s0, e0);  tt0 = pk_fma(e0, sq0, tt0);
            s1 = pk_add(s1, e1);  tt1 = pk_fma(e1, sq1, tt1);
        }
    }
    atomicAdd(&stS[col0], s0.x + s0.y);
    atomicAdd(&stT[col0], tt0.x + tt0.y);
    atomicAdd(&stS[col1], s1.x + s1.y);
    atomicAdd(&stT[col1], tt1.x + tt1.y);
}

// ---------------- rowK: col-finalize prelude + row-partial stream ----------------
// MODE 1: general. MODE 2: j==8 (rs = sum remR_9, u at coefP direct).
template<int MODE, bool SPARSE>
__global__ __launch_bounds__(512) void rowK(
    const float4* __restrict__ P1, const float4* __restrict__ P2,
    const float* __restrict__ stSr, const float* __restrict__ stTr,
    float* __restrict__ stSz, float* __restrict__ stTz,
    const float* __restrict__ remRr, float* __restrict__ remRw,
    float* __restrict__ stRS, float* __restrict__ stU,
    float* __restrict__ out,
    float coefP, float coefN)
{
    __shared__ v4f tA[CH / 2];                    // {-x0,-x1,-y0,-y1}  (P2 cols)
    __shared__ v4f tB[CH / 2];                    // {-z0,-z1, Rn0, Rn1}
    __shared__ v2f tC[CH / 2];                    // {pc0, pc1}
    __shared__ float sRn[CH], sPcs[CH];
    const int chunks = MM / CH;                   // 32
    const int bpb = (NN / 1024) * chunks;         // 64
    const int batch = blockIdx.x / bpb;
    const int rem   = blockIdx.x % bpb;
    const int rg    = rem / chunks;               // 0..1
    const int ic    = rem % chunks;
    const int t     = threadIdx.x;                // 0..511

    const int row0 = batch * NN + rg * 1024 + t;
    const int row1 = row0 + 512;
    const float4 p0 = P1[row0];                   // hoisted above prelude
    const float4 p1 = P1[row1];
    float4 a, b;
    if (t < CH / 2) {                             // hoisted staging loads
        const int gl2 = batch * MM + ic * CH + 2 * t;
        a = P2[gl2];
        b = P2[gl2 + 1];
    }

    // prelude: finalize cols of this chunk (duplicated by 2 rg-blocks; identical values)
    float c = 0.0f;
    if (t < CH) {
        const int gl = batch * MM + ic * CH + t;
        const float R  = remRr[gl];
        const float s  = stSr[gl];
        const float t2 = stTr[gl];
        const float sumr = s * R;
        const float cons = fminf(R / (sumr + EPSF), 1.0f);
        const float pcol = R * cons;
        const float Rn   = fmaxf(R - sumr * cons, 0.0f);
        remRw[gl] = Rn;
        sRn[t]  = Rn;
        sPcs[t] = pcol;
        stSz[gl] = 0.0f; stTz[gl] = 0.0f;         // zero next accumulation parity
        if (rg == 0) c = pcol * t2;               // cost contribution (once per chunk)
    }
    if (rg == 0) {
#pragma unroll
        for (int off = 32; off > 0; off >>= 1) c += __shfl_xor(c, off, 64);
        if (t == 0) atomicAdd(out + batch, c);
    }
    __syncthreads();
    if (t < CH / 2) {
        tA[t] = (v4f){-a.x, -b.x, -a.y, -b.y};
        tB[t] = (v4f){-a.z, -b.z, sRn[2*t], sRn[2*t + 1]};
        tC[t] = (v2f){sPcs[2*t], sPcs[2*t + 1]};
    }
    __syncthreads();

    const v2f ax0 = {p0.x, p0.x}, ay0 = {p0.y, p0.y}, az0 = {p0.z, p0.z};
    const v2f ax1 = {p1.x, p1.x}, ay1 = {p1.y, p1.y}, az1 = {p1.z, p1.z};
    const v2f cfN = {coefN, coefN};
    const v2f cfP = {coefP, coefP};
    v2f rs0 = {0.0f, 0.0f}, rs1 = {0.0f, 0.0f};
    v2f u0  = {0.0f, 0.0f}, u1  = {0.0f, 0.0f};
#pragma unroll 4
    for (int k = 0; k < CH / 2; ++k) {
        const v4f A = tA[k], B = tB[k];
        const v2f Pc = tC[k];
        const v2f Xn = lo2(A), Yn = hi2(A), Zn = lo2(B), Rnp = hi2(B);
        const v2f dx0 = pk_add(Xn, ax0), dy0 = pk_add(Yn, ay0), dz0 = pk_add(Zn, az0);
        const v2f d20 = pk_fma(dx0, dx0, pk_fma(dy0, dy0, pk_mul(dz0, dz0)));
        const v2f dx1 = pk_add(Xn, ax1), dy1 = pk_add(Yn, ay1), dz1 = pk_add(Zn, az1);
        const v2f d21 = pk_fma(dx1, dx1, pk_fma(dy1, dy1, pk_mul(dz1, dz1)));
        if (MODE == 1) {
            const v2f g0 = pk_mul(d20, cfN), g1 = pk_mul(d21, cfN);
            bool go = true;
            if (SPARSE) {
                const float gm = fmaxf(fmaxf(g0.x, g0.y), fmaxf(g1.x, g1.y));
                go = __ballot(gm > SKIPT) != 0ull;
            }
            if (go) {
                v2f en0, en1;
                en0.x = __builtin_amdgcn_exp2f(g0.x); en0.y = __builtin_amdgcn_exp2f(g0.y);
                en1.x = __builtin_amdgcn_exp2f(g1.x); en1.y = __builtin_amdgcn_exp2f(g1.y);
                const v2f e20 = pk_mul(en0, en0), e21 = pk_mul(en1, en1);
                const v2f e40 = pk_mul(e20, e20), e41 = pk_mul(e21, e21);
                u0  = pk_fma(e40, Pc, u0);
                u1  = pk_fma(e41, Pc, u1);
                rs0 = pk_fma(en0, Rnp, rs0);
                rs1 = pk_fma(en1, Rnp, rs1);
            }
        } else {
            const v2f g0 = pk_mul(d20, cfP), g1 = pk_mul(d21, cfP);
            v2f ep0, ep1;
            ep0.x = __builtin_amdgcn_exp2f(g0.x); ep0.y = __builtin_amdgcn_exp2f(g0.y);
            ep1.x = __builtin_amdgcn_exp2f(g1.x); ep1.y = __builtin_amdgcn_exp2f(g1.y);
            u0  = pk_fma(ep0, Pc, u0);
            u1  = pk_fma(ep1, Pc, u1);
            rs0 = pk_add(rs0, Rnp);               // e_next = exp(0) = 1
            rs1 = pk_add(rs1, Rnp);
        }
    }
    atomicAdd(&stRS[row0], rs0.x + rs0.y);
    atomicAdd(&stU[row0],  u0.x + u0.y);
    atomicAdd(&stRS[row1], rs1.x + rs1.y);
    atomicAdd(&stU[row1],  u1.x + u1.y);
}

// ---------------- finCost: cost for level 9 (no state updates) ----------------
__global__ __launch_bounds__(256) void finCost(
    const float* __restrict__ stSr, const float* __restrict__ stTr,
    const float* __restrict__ remRr, float* __restrict__ out)
{
    const int idx = blockIdx.x * 256 + threadIdx.x;
    const int batch = idx / MM;
    const float R = remRr[idx];
    const float sumr = stSr[idx] * R;
    const float cons = fminf(R / (sumr + EPSF), 1.0f);
    float c = R * cons * stTr[idx];
#pragma unroll
    for (int off = 32; off > 0; off >>= 1) c += __shfl_xor(c, off, 64);
    if ((threadIdx.x & 63) == 0) atomicAdd(out + batch, c);
}

extern "C" void kernel_launch(void* const* d_in, const int* in_sizes, int n_in,
                              void* d_out, int out_size, void* d_ws, size_t ws_size,
                              hipStream_t stream)
{
    const float* xyz1 = (const float*)d_in[0];
    const float* xyz2 = (const float*)d_in[1];
    float* out = (float*)d_out;

    const int BN = BB * NN, BM = BB * MM;
    float4* P1 = (float4*)d_ws;
    float4* P2 = P1 + BN;
    float* remL  = (float*)(P2 + BM);       // [2][BN]
    float* scale = remL + 2 * BN;           // [2][BN]
    float* remR  = scale + 2 * BN;          // [2][BM]
    float* stRS  = remR + 2 * BM;           // [2][BN]
    float* stU   = stRS + 2 * BN;           // [2][BN]
    float* stS   = stU + 2 * BN;            // [2][BM]
    float* stT   = stS + 2 * BM;            // [2][BM]

    init_kernel<<<dim3(BN / 256), dim3(256), 0, stream>>>(
        xyz1, xyz2, P1, P2, remR, stRS, stU, stS, stT, out);

    // levels: j = 7..-1 -> -(4^j), then 0.  coef = level * log2(e)
    float coef[10];
    const double lv[10] = {-16384.0, -4096.0, -1024.0, -256.0, -64.0,
                           -16.0, -4.0, -1.0, -0.25, 0.0};
    for (int i = 0; i < 10; ++i) coef[i] = (float)(lv[i] * 1.4426950408889634);

    dim3 grid(BB * 2 * (MM / CH));          // 16*2*32 = 1024 blocks
    dim3 fgrid(BM / 256);                   // 128
    dim3 blk(512);
    dim3 blk256(256);

    rowInit<<<grid, blk, 0, stream>>>(P1, P2, stRS + 1 * BN, coef[0]);

    for (int j = 0; j < 10; ++j) {
        const int p = j & 1, q = 1 - p;
        if (j == 0)
            colK<0, true><<<grid, blk, 0, stream>>>(P1, P2,
                stRS + q*BN, stU + q*BN, stRS + p*BN, stU + p*BN,
                remL + p*BN, remL + q*BN, scale + p*BN, scale + q*BN,
                stS + p*BM, stT + p*BM, coef[0]);
        else if (j <= 3)
            colK<1, true><<<grid, blk, 0, stream>>>(P1, P2,
                stRS + q*BN, stU + q*BN, stRS + p*BN, stU + p*BN,
                remL + p*BN, remL + q*BN, scale + p*BN, scale + q*BN,
                stS + p*BM, stT + p*BM, coef[j]);
        else if (j == 9)
            colK<2, false><<<grid, blk, 0, stream>>>(P1, P2,
                stRS + q*BN, stU + q*BN, stRS + p*BN, stU + p*BN,
                remL + p*BN, remL + q*BN, scale + p*BN, scale + q*BN,
                stS + p*BM, stT + p*BM, coef[9]);
        else
            colK<1, false><<<grid, blk, 0, stream>>>(P1, P2,
                stRS + q*BN, stU + q*BN, stRS + p*BN, stU + p*BN,
                remL + p*BN, remL + q*BN, scale + p*BN, scale + q*BN,
                stS + p*BM, stT + p*BM, coef[j]);

        if (j < 9) {
            if (j <= 2)
                rowK<1, true><<<grid, blk, 0, stream>>>(P1, P2,
                    stS + p*BM, stT + p*BM, stS + q*BM, stT + q*BM,
                    remR + p*BM, remR + q*BM,
                    stRS + p*BN, stU + p*BN, out, coef[j], coef[j+1]);
            else if (j < 8)
                rowK<1, false><<<grid, blk, 0, stream>>>(P1, P2,
                    stS + p*BM, stT + p*BM, stS + q*BM, stT + q*BM,
                    remR + p*BM, remR + q*BM,
                    stRS + p*BN, stU + p*BN, out, coef[j], coef[j+1]);
            else
                rowK<2, false><<<grid, blk, 0, stream>>>(P1, P2,
                    stS + p*BM, stT + p*BM, stS + q*BM, stT + q*BM,
                    remR + p*BM, remR + q*BM,
                    stRS + p*BN, stU + p*BN, out, coef[8], 0.0f);
        }
    }
    // level 9 cost: stS/stT parity 1, remR parity 1
    finCost<<<fgrid, blk256, 0, stream>>>(stS + 1*BM, stT + 1*BM, remR + 1*BM, out);
}